// Round 1
// baseline (228.920 us; speedup 1.0000x reference)
//
#include <hip/hip_runtime.h>

#define CC 64
#define NN 4096   // H*W
#define MM 1024   // pooled pixels

// ---------------------------------------------------------------------------
// prep_kernel: theta = Wth@x ; phi = maxpool2x2(Wph@x) ; g = maxpool2x2(Wg@x)
// Block = 256 threads covering 4 rows x 64 cols of one image b.
// Grid = (H/4, B) = (16, 16).
// theta written [b][8][N] (n-minor); phi written [b][m][8]; g written [b][m][32]
// (m-major so the attention kernel can load chunks as contiguous float4s).
// ---------------------------------------------------------------------------
__global__ __launch_bounds__(256) void prep_kernel(
    const float* __restrict__ x,
    const float* __restrict__ Wth,
    const float* __restrict__ Wph,
    const float* __restrict__ Wg,
    float* __restrict__ theta,   // [B][8][N]
    float* __restrict__ phiT,    // [B][M][8]
    float* __restrict__ gT)      // [B][M][32]
{
    __shared__ float wt[64 * 48];      // [c][j]: j 0..7 theta, 8..15 phi, 16..47 g
    __shared__ float pool[256 * 40];   // per-pixel phi/g values before 2x2 max

    const int tid = threadIdx.x;
    const int b  = blockIdx.y;
    const int h0 = blockIdx.x * 4;

    // stage weights transposed: wt[c*48 + j]
    for (int idx = tid; idx < 64 * 48; idx += 256) {
        const int c = idx / 48, j = idx % 48;
        float v;
        if (j < 8)       v = Wth[j * 64 + c];
        else if (j < 16) v = Wph[(j - 8) * 64 + c];
        else             v = Wg[(j - 16) * 64 + c];
        wt[c * 48 + j] = v;
    }
    __syncthreads();

    const int r = tid >> 6;          // row within 4-row strip
    const int w = tid & 63;          // column
    const int n = (h0 + r) * 64 + w; // pixel index
    const float* xb = x + (size_t)b * CC * NN + n;

    float acc[48];
#pragma unroll
    for (int j = 0; j < 48; ++j) acc[j] = 0.f;

    for (int c = 0; c < 64; ++c) {
        const float v = xb[(size_t)c * NN];     // coalesced across lanes
        const float* wrow = &wt[c * 48];        // broadcast ds_read_b128s
#pragma unroll
        for (int j = 0; j < 48; ++j) acc[j] += wrow[j] * v;
    }

    // theta out (no pooling)
    float* thb = theta + (size_t)b * 8 * NN + n;
#pragma unroll
    for (int o = 0; o < 8; ++o) thb[(size_t)o * NN] = acc[o];

    // stash per-pixel phi/g for pooling
#pragma unroll
    for (int j = 8; j < 48; ++j) pool[tid * 40 + (j - 8)] = acc[j];
    __syncthreads();

    // 2x2 max-pool: 2 pooled rows x 32 pooled cols x 40 channels = 2560 values
    for (int idx = tid; idx < 2560; idx += 256) {
        const int j  = idx % 40;
        const int pq = idx / 40;        // 0..63
        const int rp = pq >> 5;         // pooled row within strip (0..1)
        const int wp = pq & 31;         // pooled col
        const int base = ((2 * rp) * 64 + 2 * wp) * 40 + j;
        const float v0 = pool[base];
        const float v1 = pool[base + 40];
        const float v2 = pool[base + 64 * 40];
        const float v3 = pool[base + 64 * 40 + 40];
        const float v = fmaxf(fmaxf(v0, v1), fmaxf(v2, v3));
        const int m = (h0 / 2 + rp) * 32 + wp;
        if (j < 8) phiT[((size_t)b * MM + m) * 8 + j] = v;
        else       gT[((size_t)b * MM + m) * 32 + (j - 8)] = v;
    }
}

// ---------------------------------------------------------------------------
// attn_kernel: per query pixel n, stream over all M keys:
//   s_m = sum_k th[k]*phi[m][k]; e=exp(s); Z+=e; og[g]+=e*g[m][g]
// then out[b,c,n] = x[b,c,n] + sigma * sum_g Wa[c][g]*og[g]/Z
// Block = 256 threads = 256 queries; grid = (N/256, B) = (16,16).
// ---------------------------------------------------------------------------
__global__ __launch_bounds__(256) void attn_kernel(
    const float* __restrict__ x,
    const float* __restrict__ theta,   // [B][8][N]
    const float* __restrict__ phiT,    // [B][M][8]
    const float* __restrict__ gT,      // [B][M][32]
    const float* __restrict__ Wa,      // [64][32]
    const float* __restrict__ sigma,   // [1]
    float* __restrict__ out)           // [B][64][N]
{
    __shared__ float phi_s[256 * 8];   // [m_local][k]
    __shared__ float g_s[256 * 32];    // [m_local][g]
    __shared__ float wa_s[64 * 32];    // [o][g]

    const int tid = threadIdx.x;
    const int b = blockIdx.y;
    const int n = blockIdx.x * 256 + tid;

    for (int i = tid; i < 2048; i += 256) wa_s[i] = Wa[i];

    float th[8];
#pragma unroll
    for (int k = 0; k < 8; ++k)
        th[k] = theta[(size_t)b * 8 * NN + (size_t)k * NN + n];

    float og[32];
#pragma unroll
    for (int g = 0; g < 32; ++g) og[g] = 0.f;
    float Z = 0.f;

    const float4* phi_src = (const float4*)(phiT + (size_t)b * MM * 8);
    const float4* g_src   = (const float4*)(gT + (size_t)b * MM * 32);

    for (int mc = 0; mc < 4; ++mc) {
        __syncthreads();   // protect previous chunk's readers
        // phi chunk: 256*8 floats = 512 float4s, contiguous
        {
            float4* dst = (float4*)phi_s;
            const float4* src = phi_src + mc * 512;
#pragma unroll
            for (int it = 0; it < 2; ++it) dst[tid + 256 * it] = src[tid + 256 * it];
        }
        // g chunk: 256*32 floats = 2048 float4s, contiguous
        {
            float4* dst = (float4*)g_s;
            const float4* src = g_src + mc * 2048;
#pragma unroll
            for (int it = 0; it < 8; ++it) dst[tid + 256 * it] = src[tid + 256 * it];
        }
        __syncthreads();

        for (int m = 0; m < 256; ++m) {
            float s = 0.f;
#pragma unroll
            for (int k = 0; k < 8; ++k) s += th[k] * phi_s[m * 8 + k];
            const float e = __expf(s);
            Z += e;
            const float* gr = &g_s[m * 32];
#pragma unroll
            for (int g = 0; g < 32; ++g) og[g] += e * gr[g];
        }
    }

    const float rz = 1.f / Z;
#pragma unroll
    for (int g = 0; g < 32; ++g) og[g] *= rz;

    const float sg = sigma[0];
    for (int o = 0; o < 64; ++o) {
        float a = 0.f;
#pragma unroll
        for (int g = 0; g < 32; ++g) a += wa_s[o * 32 + g] * og[g];
        const size_t oi = (size_t)b * CC * NN + (size_t)o * NN + n;
        out[oi] = x[oi] + sg * a;
    }
}

extern "C" void kernel_launch(void* const* d_in, const int* in_sizes, int n_in,
                              void* d_out, int out_size, void* d_ws, size_t ws_size,
                              hipStream_t stream) {
    const float* x      = (const float*)d_in[0];
    const float* W_th   = (const float*)d_in[1];
    const float* W_ph   = (const float*)d_in[2];
    const float* W_g    = (const float*)d_in[3];
    const float* W_attn = (const float*)d_in[4];
    const float* sigma  = (const float*)d_in[5];
    float* out = (float*)d_out;

    const int B = 16;
    float* theta = (float*)d_ws;                       // B*8*N  = 524288 floats
    float* phiT  = theta + (size_t)B * 8 * NN;         // B*M*8  = 131072 floats
    float* gT    = phiT + (size_t)B * MM * 8;          // B*M*32 = 524288 floats

    prep_kernel<<<dim3(16, 16), 256, 0, stream>>>(x, W_th, W_ph, W_g,
                                                  theta, phiT, gT);
    attn_kernel<<<dim3(16, 16), 256, 0, stream>>>(x, theta, phiT, gT,
                                                  W_attn, sigma, out);
}

// Round 2
// 189.403 us; speedup vs baseline: 1.2086x; 1.2086x over previous
//
#include <hip/hip_runtime.h>
#include <hip/hip_bf16.h>

#define CC 64
#define NN 4096   // H*W
#define MM 1024   // pooled pixels

// ---------------------------------------------------------------------------
// prep_kernel: theta = Wth@x ; phi = maxpool2x2(Wph@x) ; g = maxpool2x2(Wg@x)
// Block = 256 threads covering 4 rows x 64 cols of one image b.
// Grid = (H/4, B) = (16, 16).
// c-loop unrolled x16 so 16 global loads are in flight per wave (round 1 was
// 1-in-flight -> ~0.7 TB/s; this should reach ~3-4 TB/s on the 64 MB x read).
// ---------------------------------------------------------------------------
__global__ __launch_bounds__(256) void prep_kernel(
    const float* __restrict__ x,
    const float* __restrict__ Wth,
    const float* __restrict__ Wph,
    const float* __restrict__ Wg,
    float* __restrict__ theta,   // [B][8][N]
    float* __restrict__ phiT,    // [B][M][8]
    float* __restrict__ gT)      // [B][M][32]
{
    __shared__ float wt[64 * 48];      // [c][j]: j 0..7 theta, 8..15 phi, 16..47 g
    __shared__ float pool[256 * 40];   // per-pixel phi/g values before 2x2 max

    const int tid = threadIdx.x;
    const int b  = blockIdx.y;
    const int h0 = blockIdx.x * 4;

    for (int idx = tid; idx < 64 * 48; idx += 256) {
        const int c = idx / 48, j = idx % 48;
        float v;
        if (j < 8)       v = Wth[j * 64 + c];
        else if (j < 16) v = Wph[(j - 8) * 64 + c];
        else             v = Wg[(j - 16) * 64 + c];
        wt[c * 48 + j] = v;
    }
    __syncthreads();

    const int r = tid >> 6;
    const int w = tid & 63;
    const int n = (h0 + r) * 64 + w;
    const float* xb = x + (size_t)b * CC * NN + n;

    float acc[48];
#pragma unroll
    for (int j = 0; j < 48; ++j) acc[j] = 0.f;

    for (int c0 = 0; c0 < 64; c0 += 16) {
        float xv[16];
#pragma unroll
        for (int u = 0; u < 16; ++u) xv[u] = xb[(size_t)(c0 + u) * NN];
#pragma unroll
        for (int u = 0; u < 16; ++u) {
            const float* wrow = &wt[(c0 + u) * 48];
#pragma unroll
            for (int j = 0; j < 48; ++j) acc[j] += wrow[j] * xv[u];
        }
    }

    float* thb = theta + (size_t)b * 8 * NN + n;
#pragma unroll
    for (int o = 0; o < 8; ++o) thb[(size_t)o * NN] = acc[o];

#pragma unroll
    for (int j = 8; j < 48; ++j) pool[tid * 40 + (j - 8)] = acc[j];
    __syncthreads();

    for (int idx = tid; idx < 2560; idx += 256) {
        const int j  = idx % 40;
        const int pq = idx / 40;
        const int rp = pq >> 5;
        const int wp = pq & 31;
        const int base = ((2 * rp) * 64 + 2 * wp) * 40 + j;
        const float v0 = pool[base];
        const float v1 = pool[base + 40];
        const float v2 = pool[base + 64 * 40];
        const float v3 = pool[base + 64 * 40 + 40];
        const float v = fmaxf(fmaxf(v0, v1), fmaxf(v2, v3));
        const int m = (h0 / 2 + rp) * 32 + wp;
        if (j < 8) phiT[((size_t)b * MM + m) * 8 + j] = v;
        else       gT[((size_t)b * MM + m) * 32 + (j - 8)] = v;
    }
}

// ---------------------------------------------------------------------------
// attn_partial: each block handles 1024 queries (4 per thread) x (M/S) keys,
// accumulating unnormalized og[32] = sum_m e_m * g[m][:] and Z = sum_m e_m.
// 4 queries/thread amortizes the per-key LDS broadcast reads 4x; S=8 splits
// give 2048 waves = 8 waves/CU = 2/SIMD for latency hiding.
// Partials: ogp packed bf16x2 [b][s][16][N], zp f32 [b][s][N].
// Grid = (4, 16, S), block = 256. ~195 VGPR -> 2 waves/SIMD (launch_bounds).
// ---------------------------------------------------------------------------
__global__ __launch_bounds__(256, 2) void attn_partial(
    const float* __restrict__ theta,   // [B][8][N]
    const float* __restrict__ phiT,    // [B][M][8]
    const float* __restrict__ gT,      // [B][M][32]
    __hip_bfloat162* __restrict__ ogp, // [B][S][16][N]
    float* __restrict__ zp,            // [B][S][N]
    int S, int nchunks)                // nchunks = (M/S)/128
{
    __shared__ float phi_s[128 * 8];   // 4 KB
    __shared__ float g_s[128 * 32];    // 16 KB

    const int tid = threadIdx.x;
    const int b  = blockIdx.y;
    const int n0 = blockIdx.x * 1024;
    const int s  = blockIdx.z;

    // theta fragments for 4 queries, pre-scaled by log2(e) so exp == exp2
    float th[4][8];
#pragma unroll
    for (int q = 0; q < 4; ++q)
#pragma unroll
        for (int k = 0; k < 8; ++k)
            th[q][k] = theta[((size_t)b * 8 + k) * NN + n0 + q * 256 + tid] * 1.44269504f;

    float og[4][32];
#pragma unroll
    for (int q = 0; q < 4; ++q)
#pragma unroll
        for (int g = 0; g < 32; ++g) og[q][g] = 0.f;
    float Z[4] = {0.f, 0.f, 0.f, 0.f};

    for (int cc = 0; cc < nchunks; ++cc) {
        const int c = s * nchunks + cc;   // 128-key chunk index
        __syncthreads();
        {
            const float4* ps = (const float4*)phiT + ((size_t)b * MM + c * 128) * 2;
            ((float4*)phi_s)[tid] = ps[tid];
            const float4* gs = (const float4*)gT + ((size_t)b * MM + c * 128) * 8;
#pragma unroll
            for (int it = 0; it < 4; ++it)
                ((float4*)g_s)[tid + 256 * it] = gs[tid + 256 * it];
        }
        __syncthreads();

        for (int m = 0; m < 128; ++m) {
            float p[8];
#pragma unroll
            for (int k = 0; k < 8; ++k) p[k] = phi_s[m * 8 + k];
            float e[4];
#pragma unroll
            for (int q = 0; q < 4; ++q) {
                float sc = 0.f;
#pragma unroll
                for (int k = 0; k < 8; ++k) sc += th[q][k] * p[k];
                e[q] = __builtin_amdgcn_exp2f(sc);
                Z[q] += e[q];
            }
            const float* gr = &g_s[m * 32];
#pragma unroll
            for (int g = 0; g < 32; ++g) {
                const float gv = gr[g];
#pragma unroll
                for (int q = 0; q < 4; ++q) og[q][g] += e[q] * gv;
            }
        }
    }

    const size_t pb = (size_t)b * S + s;
#pragma unroll
    for (int q = 0; q < 4; ++q) {
        const int n = n0 + q * 256 + tid;
        zp[pb * NN + n] = Z[q];
#pragma unroll
        for (int g2 = 0; g2 < 16; ++g2) {
            __hip_bfloat162 pk;
            pk.x = __float2bfloat16(og[q][2 * g2]);
            pk.y = __float2bfloat16(og[q][2 * g2 + 1]);
            ogp[(pb * 16 + g2) * NN + n] = pk;
        }
    }
}

// ---------------------------------------------------------------------------
// combine_kernel: sum S partials, normalize by total Z, apply W_attn and the
// residual. Grid = (16, 16), block = 256 (thread = query).
// ---------------------------------------------------------------------------
__global__ __launch_bounds__(256) void combine_kernel(
    const float* __restrict__ x,
    const __hip_bfloat162* __restrict__ ogp,
    const float* __restrict__ zp,
    const float* __restrict__ Wa,      // [64][32]
    const float* __restrict__ sigma,
    float* __restrict__ out,
    int S)
{
    __shared__ float wa_s[64 * 32];
    const int tid = threadIdx.x;
    const int b = blockIdx.y;
    const int n = blockIdx.x * 256 + tid;

    for (int i = tid; i < 2048; i += 256) wa_s[i] = Wa[i];

    float og[32];
#pragma unroll
    for (int g = 0; g < 32; ++g) og[g] = 0.f;
    float Z = 0.f;

    for (int s = 0; s < S; ++s) {
        const size_t pb = (size_t)b * S + s;
        Z += zp[pb * NN + n];
#pragma unroll
        for (int g2 = 0; g2 < 16; ++g2) {
            const __hip_bfloat162 v = ogp[(pb * 16 + g2) * NN + n];
            og[2 * g2]     += __bfloat162float(v.x);
            og[2 * g2 + 1] += __bfloat162float(v.y);
        }
    }
    __syncthreads();

    const float rz = 1.f / Z;
#pragma unroll
    for (int g = 0; g < 32; ++g) og[g] *= rz;

    const float sg = sigma[0];
#pragma unroll 8
    for (int o = 0; o < 64; ++o) {
        float a = 0.f;
#pragma unroll
        for (int g = 0; g < 32; ++g) a += wa_s[o * 32 + g] * og[g];
        const size_t oi = ((size_t)b * CC + o) * NN + n;
        out[oi] = x[oi] + sg * a;
    }
}

extern "C" void kernel_launch(void* const* d_in, const int* in_sizes, int n_in,
                              void* d_out, int out_size, void* d_ws, size_t ws_size,
                              hipStream_t stream) {
    const float* x      = (const float*)d_in[0];
    const float* W_th   = (const float*)d_in[1];
    const float* W_ph   = (const float*)d_in[2];
    const float* W_g    = (const float*)d_in[3];
    const float* W_attn = (const float*)d_in[4];
    const float* sigma  = (const float*)d_in[5];
    float* out = (float*)d_out;

    const int B = 16;
    const size_t prepF = (size_t)B * 8 * NN + (size_t)B * MM * 8 + (size_t)B * MM * 32;

    // pick split count that fits the workspace: per (b,s): ogp 16*N*4 B + zp N*4 B
    int S = 8;
    while (S > 1) {
        const size_t need = prepF * 4 + (size_t)S * B * NN * (16 * 4 + 4);
        if (need <= ws_size) break;
        S >>= 1;
    }
    const int nchunks = (MM / S) / 128;

    float* theta = (float*)d_ws;                       // B*8*N floats
    float* phiT  = theta + (size_t)B * 8 * NN;         // B*M*8 floats
    float* gT    = phiT + (size_t)B * MM * 8;          // B*M*32 floats
    __hip_bfloat162* ogp = (__hip_bfloat162*)(gT + (size_t)B * MM * 32);
    float* zp = (float*)(ogp + (size_t)B * S * 16 * NN);

    prep_kernel<<<dim3(16, 16), 256, 0, stream>>>(x, W_th, W_ph, W_g,
                                                  theta, phiT, gT);
    attn_partial<<<dim3(4, 16, S), 256, 0, stream>>>(theta, phiT, gT,
                                                     ogp, zp, S, nchunks);
    combine_kernel<<<dim3(16, 16), 256, 0, stream>>>(x, ogp, zp, W_attn, sigma,
                                                     out, S);
}

// Round 4
// 137.114 us; speedup vs baseline: 1.6696x; 1.3813x over previous
//
#include <hip/hip_runtime.h>
#include <hip/hip_bf16.h>

#define CC 64
#define NN 4096   // H*W
#define MM 1024   // pooled pixels

typedef __attribute__((ext_vector_type(8))) short short8;   // 8 bf16 = 4 VGPRs
typedef __attribute__((ext_vector_type(4))) float float4v;  // MFMA C/D frag

__device__ inline unsigned short f2bf(float f) {
    union { float f; unsigned u; } v; v.f = f;
    unsigned r = v.u + 0x7fff + ((v.u >> 16) & 1);   // RNE
    return (unsigned short)(r >> 16);
}

// ---------------------------------------------------------------------------
// prep_kernel: theta/phi/g 1x1 convs + 2x2 maxpool, bf16 outputs laid out for
// the MFMA attention kernel:
//   thT [b][n][8]  (theta^T, pre-scaled by log2(e) so exp == exp2)
//   phiP[b][m][8]
//   gP  [b][gi][m] (gi-major so PV A-fragments are contiguous key runs)
// ---------------------------------------------------------------------------
__global__ __launch_bounds__(256) void prep_kernel(
    const float* __restrict__ x,
    const float* __restrict__ Wth,
    const float* __restrict__ Wph,
    const float* __restrict__ Wg,
    unsigned short* __restrict__ thT,
    unsigned short* __restrict__ phiP,
    unsigned short* __restrict__ gP)
{
    __shared__ float wt[64 * 48];
    __shared__ float pool[256 * 40];

    const int tid = threadIdx.x;
    const int b  = blockIdx.y;
    const int h0 = blockIdx.x * 4;

    for (int idx = tid; idx < 64 * 48; idx += 256) {
        const int c = idx / 48, j = idx % 48;
        float v;
        if (j < 8)       v = Wth[j * 64 + c];
        else if (j < 16) v = Wph[(j - 8) * 64 + c];
        else             v = Wg[(j - 16) * 64 + c];
        wt[c * 48 + j] = v;
    }
    __syncthreads();

    const int r = tid >> 6;
    const int w = tid & 63;
    const int n = (h0 + r) * 64 + w;
    const float* xb = x + (size_t)b * CC * NN + n;

    float acc[48];
#pragma unroll
    for (int j = 0; j < 48; ++j) acc[j] = 0.f;

    for (int c0 = 0; c0 < 64; c0 += 16) {
        float xv[16];
#pragma unroll
        for (int u = 0; u < 16; ++u) xv[u] = xb[(size_t)(c0 + u) * NN];
#pragma unroll
        for (int u = 0; u < 16; ++u) {
            const float* wrow = &wt[(c0 + u) * 48];
#pragma unroll
            for (int j = 0; j < 48; ++j) acc[j] += wrow[j] * xv[u];
        }
    }

    // theta^T bf16, scaled by log2(e)
    {
        union { unsigned short s[8]; uint4 v; } pk;
#pragma unroll
        for (int j = 0; j < 8; ++j) pk.s[j] = f2bf(acc[j] * 1.44269504f);
        *(uint4*)&thT[((size_t)b * NN + n) * 8] = pk.v;
    }

#pragma unroll
    for (int j = 8; j < 48; ++j) pool[tid * 40 + (j - 8)] = acc[j];
    __syncthreads();

    for (int idx = tid; idx < 2560; idx += 256) {
        const int j  = idx % 40;
        const int pq = idx / 40;
        const int rp = pq >> 5;
        const int wp = pq & 31;
        const int base = ((2 * rp) * 64 + 2 * wp) * 40 + j;
        const float v0 = pool[base];
        const float v1 = pool[base + 40];
        const float v2 = pool[base + 64 * 40];
        const float v3 = pool[base + 64 * 40 + 40];
        const float v = fmaxf(fmaxf(v0, v1), fmaxf(v2, v3));
        const int m = (h0 / 2 + rp) * 32 + wp;
        if (j < 8) phiP[((size_t)b * MM + m) * 8 + j] = f2bf(v);
        else       gP[((size_t)b * 32 + (j - 8)) * MM + m] = f2bf(v);
    }
}

// ---------------------------------------------------------------------------
// attn_mfma: block = 16 queries x all 1024 keys, 4 waves each own a 64-key
// strip of every 256-key chunk. Scores via mfma_16x16x32_bf16 (K padded
// 8->32 with zero frags); P -> wave-private LDS -> PV B-fragment; O[32gi x
// 16q] accumulates in C-layout regs. Cross-wave LDS reduce, then VALU
// epilogue applies 1/Z, W_attn, sigma and the residual.
// Grid = (N/16, B) = (256, 16), block = 256.
// ---------------------------------------------------------------------------
__global__ __launch_bounds__(256) void attn_mfma(
    const unsigned short* __restrict__ thT,   // [B][N][8]
    const unsigned short* __restrict__ phiP,  // [B][M][8]
    const unsigned short* __restrict__ gP,    // [B][32][M]
    const float* __restrict__ x,
    const float* __restrict__ Wa,             // [64][32]
    const float* __restrict__ sigma,
    float* __restrict__ out)
{
    constexpr int GP  = 260;  // g_s pitch (bf16): 520 B/row -> 2-way banks (free)
    constexpr int PWP = 40;   // pw pitch  (bf16): 80 B/row

    __shared__ __align__(16) unsigned short phi_s[256 * 8];   // 4 KB
    __shared__ __align__(16) unsigned short g_s[32 * GP];     // 16.25 KB
    __shared__ __align__(16) unsigned short pw[4][16 * PWP];  // 5 KB (wave-private)
    __shared__ float red[4][32 * 20];                          // 10 KB
    __shared__ float zsl[4][16];
    __shared__ float wa_s[64 * 32];                            // 8 KB

    const int tid  = threadIdx.x;
    const int lane = tid & 63;
    const int wv   = tid >> 6;
    const int q    = lane & 15;
    const int quad = lane >> 4;
    const int b    = blockIdx.y;
    const int n0   = blockIdx.x * 16;

    for (int i = tid; i < 2048; i += 256) wa_s[i] = Wa[i];

    // constant theta B-frag: B[k=quad*8+j][n=q]; only quad 0 holds real k (0..7)
    short8 zero8 = {0, 0, 0, 0, 0, 0, 0, 0};
    short8 bth = zero8;
    if (quad == 0) bth = *(const short8*)&thT[((size_t)b * NN + n0 + q) * 8];

    float4v acc0 = {0.f, 0.f, 0.f, 0.f};
    float4v acc1 = {0.f, 0.f, 0.f, 0.f};
    float zacc = 0.f;

    unsigned short* pws = &pw[wv][0];

    for (int ch = 0; ch < 4; ++ch) {
        __syncthreads();
        // stage phi chunk: 256 keys x 8 bf16 (16B per thread)
        *(uint4*)&phi_s[tid * 8] =
            *(const uint4*)&phiP[((size_t)b * MM + ch * 256 + tid) * 8];
        // stage g chunk: 32 rows x 256 bf16 = 2048 uint2s (FIXED: was covering
        // only keys 0..127 of each row -> NaN from uninitialized LDS)
#pragma unroll
        for (int it = 0; it < 8; ++it) {
            const int idx = tid + 256 * it;
            const int row = idx >> 6, c4 = idx & 63;
            *(uint2*)&g_s[row * GP + c4 * 4] =
                *(const uint2*)&gP[((size_t)b * 32 + row) * MM + ch * 256 + c4 * 4];
        }
        __syncthreads();

        const int kk0 = wv * 64;   // wave's strip within the chunk
#pragma unroll
        for (int t8 = 0; t8 < 2; ++t8) {
            const int kbase = kk0 + t8 * 32;

            // two 16-key score tiles: D[key][q]
            float4v sc[2];
#pragma unroll
            for (int st = 0; st < 2; ++st) {
                short8 af = zero8;
                if (quad == 0)
                    af = *(const short8*)&phi_s[(kbase + st * 16 + q) * 8];
                float4v cz = {0.f, 0.f, 0.f, 0.f};
                sc[st] = __builtin_amdgcn_mfma_f32_16x16x32_bf16(af, bth, cz, 0, 0, 0);
            }

            // exp + Z + pack P into wave-private LDS (pw[q][key32])
#pragma unroll
            for (int st = 0; st < 2; ++st) {
                float e[4];
#pragma unroll
                for (int r = 0; r < 4; ++r) {
                    e[r] = __builtin_amdgcn_exp2f(sc[st][r]);
                    zacc += e[r];
                }
                union { unsigned short s[4]; uint2 v; } pk;
#pragma unroll
                for (int r = 0; r < 4; ++r) pk.s[r] = f2bf(e[r]);
                *(uint2*)&pws[q * PWP + st * 16 + quad * 4] = pk.v;
            }

            // in-wave LDS visibility: drain lgkmcnt, pin scheduling
            __builtin_amdgcn_wave_barrier();
            __builtin_amdgcn_s_waitcnt(0xc07f);   // lgkmcnt(0) only
            __builtin_amdgcn_wave_barrier();

            // B-frag: B[k=quad*8+j][n=q] from pw
            union { short8 s; uint2 u[2]; } bp;
            bp.u[0] = *(const uint2*)&pws[q * PWP + quad * 8];
            bp.u[1] = *(const uint2*)&pws[q * PWP + quad * 8 + 4];

            // PV: two gi-tiles, K = 32 keys in one MFMA each
#pragma unroll
            for (int gt = 0; gt < 2; ++gt) {
                const unsigned short* gr =
                    &g_s[(gt * 16 + q) * GP + kbase + quad * 8];
                union { short8 s; uint2 u[2]; } ag;
                ag.u[0] = *(const uint2*)gr;
                ag.u[1] = *(const uint2*)(gr + 4);
                if (gt == 0)
                    acc0 = __builtin_amdgcn_mfma_f32_16x16x32_bf16(ag.s, bp.s, acc0, 0, 0, 0);
                else
                    acc1 = __builtin_amdgcn_mfma_f32_16x16x32_bf16(ag.s, bp.s, acc1, 0, 0, 0);
            }
        }
    }

    // stash per-wave partials: O rows gi = quad*4+r (+16), col q
    {
        float* rd = &red[wv][0];
#pragma unroll
        for (int r = 0; r < 4; ++r) {
            rd[(quad * 4 + r) * 20 + q]        = acc0[r];
            rd[(16 + quad * 4 + r) * 20 + q]   = acc1[r];
        }
        float zz = zacc;
        zz += __shfl_xor(zz, 16, 64);
        zz += __shfl_xor(zz, 32, 64);
        if (lane < 16) zsl[wv][q] = zz;
    }
    __syncthreads();

    // pass 1: reduce the 4 wave-slabs, fold 1/Z
    for (int idx = tid; idx < 512; idx += 256) {
        const int gi = idx >> 4, qq = idx & 15;
        const float z = zsl[0][qq] + zsl[1][qq] + zsl[2][qq] + zsl[3][qq];
        const float o = red[0][gi * 20 + qq] + red[1][gi * 20 + qq] +
                        red[2][gi * 20 + qq] + red[3][gi * 20 + qq];
        red[0][gi * 20 + qq] = o / z;
    }
    __syncthreads();

    // pass 2: out[o][n] = x + sigma * Wa[o][:] . Obar[:][q]
    {
        const int qq = tid & 15;
        const int os = tid >> 4;          // 16 groups of 4 output channels
        float a[4] = {0.f, 0.f, 0.f, 0.f};
#pragma unroll 8
        for (int gi = 0; gi < 32; ++gi) {
            const float on = red[0][gi * 20 + qq];
#pragma unroll
            for (int i = 0; i < 4; ++i)
                a[i] += wa_s[(os * 4 + i) * 32 + gi] * on;
        }
        const float sg = sigma[0];
#pragma unroll
        for (int i = 0; i < 4; ++i) {
            const size_t oi = ((size_t)b * CC + os * 4 + i) * NN + n0 + qq;
            out[oi] = x[oi] + sg * a[i];
        }
    }
}

extern "C" void kernel_launch(void* const* d_in, const int* in_sizes, int n_in,
                              void* d_out, int out_size, void* d_ws, size_t ws_size,
                              hipStream_t stream) {
    const float* x      = (const float*)d_in[0];
    const float* W_th   = (const float*)d_in[1];
    const float* W_ph   = (const float*)d_in[2];
    const float* W_g    = (const float*)d_in[3];
    const float* W_attn = (const float*)d_in[4];
    const float* sigma  = (const float*)d_in[5];
    float* out = (float*)d_out;

    const int B = 16;
    unsigned short* thT  = (unsigned short*)d_ws;              // B*N*8
    unsigned short* phiP = thT + (size_t)B * NN * 8;           // B*M*8
    unsigned short* gP   = phiP + (size_t)B * MM * 8;          // B*32*M

    prep_kernel<<<dim3(16, 16), 256, 0, stream>>>(x, W_th, W_ph, W_g,
                                                  thT, phiP, gP);
    attn_mfma<<<dim3(256, 16), 256, 0, stream>>>(thT, phiP, gP, x,
                                                 W_attn, sigma, out);
}

// Round 6
// 115.099 us; speedup vs baseline: 1.9889x; 1.1913x over previous
//
#include <hip/hip_runtime.h>
#include <hip/hip_bf16.h>

#define CC 64
#define NN 4096   // H*W
#define MM 1024   // pooled pixels

typedef __attribute__((ext_vector_type(4))) short s4b;      // 4 bf16 = 2 VGPRs
typedef __attribute__((ext_vector_type(4))) float float4v;  // MFMA C/D frag

__device__ inline unsigned short f2bf(float f) {
    union { float f; unsigned u; } v; v.f = f;
    unsigned r = v.u + 0x7fff + ((v.u >> 16) & 1);   // RNE
    return (unsigned short)(r >> 16);
}

__device__ inline float4v mfma16(s4b a, s4b b, float4v c) {
#if __has_builtin(__builtin_amdgcn_mfma_f32_16x16x16bf16_1k)
    return __builtin_amdgcn_mfma_f32_16x16x16bf16_1k(a, b, c, 0, 0, 0);
#else
    float4v d;
    asm volatile("v_mfma_f32_16x16x16_bf16 %0, %1, %2, %3"
                 : "=v"(d) : "v"(a), "v"(b), "v"(c));
    return d;
#endif
}

// ---------------------------------------------------------------------------
// prep_kernel v2: 2 c-halves per pixel (reduced via LDS) -> 512 blocks,
// 8 waves/CU, 16 loads in flight per wave: BW-bound on the 64 MB x read.
// Block: 256 thr = 128 pixels (2 rows x 64 cols) x 2 c-halves. Grid (32,16).
// Outputs: thT [b][n][8] bf16 (x log2e); phiP [b][m][8]; gP [b][gi][m].
// ---------------------------------------------------------------------------
__global__ __launch_bounds__(256) void prep_kernel(
    const float* __restrict__ x,
    const float* __restrict__ Wth,
    const float* __restrict__ Wph,
    const float* __restrict__ Wg,
    unsigned short* __restrict__ thT,
    unsigned short* __restrict__ phiP,
    unsigned short* __restrict__ gP)
{
    __shared__ float wt[64 * 48];       // 12.3 KB
    __shared__ float buf[128 * 49];     // 25.1 KB (partials, then pool)

    const int tid  = threadIdx.x;
    const int b    = blockIdx.y;
    const int hp   = blockIdx.x;        // row-pair 0..31
    const int pix  = tid & 127;         // 2 rows x 64 cols
    const int half = tid >> 7;          // c-half (wave-uniform)

    for (int idx = tid; idx < 64 * 48; idx += 256) {
        const int c = idx / 48, j = idx % 48;
        float v;
        if (j < 8)       v = Wth[j * 64 + c];
        else if (j < 16) v = Wph[(j - 8) * 64 + c];
        else             v = Wg[(j - 16) * 64 + c];
        wt[c * 48 + j] = v;
    }
    __syncthreads();

    const int n = (2 * hp + (pix >> 6)) * 64 + (pix & 63);
    const float* xb = x + (size_t)b * CC * NN + (size_t)half * 32 * NN + n;

    float acc[48];
#pragma unroll
    for (int j = 0; j < 48; ++j) acc[j] = 0.f;

#pragma unroll
    for (int c0 = 0; c0 < 32; c0 += 16) {
        float xv[16];
#pragma unroll
        for (int u = 0; u < 16; ++u) xv[u] = xb[(size_t)(c0 + u) * NN];
#pragma unroll
        for (int u = 0; u < 16; ++u) {
            const float* wrow = &wt[(half * 32 + c0 + u) * 48];
#pragma unroll
            for (int j = 0; j < 48; ++j) acc[j] += wrow[j] * xv[u];
        }
    }

    if (half == 1) {
#pragma unroll
        for (int j = 0; j < 48; ++j) buf[pix * 49 + j] = acc[j];
    }
    __syncthreads();

    if (half == 0) {
#pragma unroll
        for (int j = 0; j < 48; ++j) acc[j] += buf[pix * 49 + j];
        // theta out (bf16, scaled by log2 e)
        union { unsigned short s[8]; uint4 v; } pk;
#pragma unroll
        for (int j = 0; j < 8; ++j) pk.s[j] = f2bf(acc[j] * 1.44269504f);
        *(uint4*)&thT[((size_t)b * NN + n) * 8] = pk.v;
        // stash phi/g pre-pool values (overwrite own partial region)
#pragma unroll
        for (int j = 0; j < 40; ++j) buf[pix * 49 + j] = acc[8 + j];
    }
    __syncthreads();

    // 2x2 pool: 32 pooled cols x 40 channels
    for (int idx = tid; idx < 1280; idx += 256) {
        const int pm = idx & 31;        // pooled col
        const int j  = idx >> 5;        // channel 0..39
        const int p00 = 2 * pm, p10 = 64 + 2 * pm;
        const float v = fmaxf(fmaxf(buf[p00 * 49 + j], buf[(p00 + 1) * 49 + j]),
                              fmaxf(buf[p10 * 49 + j], buf[(p10 + 1) * 49 + j]));
        const int m = hp * 32 + pm;
        if (j < 8) phiP[((size_t)b * MM + m) * 8 + j] = f2bf(v);
        else       gP[((size_t)b * 32 + (j - 8)) * MM + m] = f2bf(v);
    }
}

// ---------------------------------------------------------------------------
// attn_mfma v3b: block = 64 queries (4 waves x 16), each wave runs ALL 1024
// keys for its 16 queries. K=16 MFMAs keep P entirely in registers:
//   score D layout (lane(q,quad): keys quad*4+r) == PV A layout (k=quad*4+j).
// Fixes vs v3: GP=264 so g-row pitch (528 B) is 16B-aligned for uint4
// staging; phi pad zeroed every chunk (key-255 A-frag overread was hitting
// uninitialized LDS -> NaN via junk*0 in the MFMA); union/wa_s __align__(16).
// Grid (64,16), block 256.
// ---------------------------------------------------------------------------
__global__ __launch_bounds__(256) void attn_mfma(
    const unsigned short* __restrict__ thT,   // [B][N][8]
    const unsigned short* __restrict__ phiP,  // [B][M][8]
    const unsigned short* __restrict__ gP,    // [B][32][M]
    const float* __restrict__ x,
    const float* __restrict__ Wa,             // [64][32]
    const float* __restrict__ sigma,
    float* __restrict__ out)
{
    constexpr int GP = 264;   // g_s pitch (bf16): 528 B = 33x16 -> aligned rows;
                              // bg read banks: 4*c15 mod 32 -> 2-way (free, m136)
    constexpr int OP = 36;    // obar pitch in f32

    __shared__ __align__(16) union {
        struct {
            unsigned short phi[256 * 8 + 16];  // pad: key-255 quad2/3 overread
            unsigned short g[32 * GP];
        } m;                                    // 21.0 KB
        float obar[64 * OP];                    // 9.2 KB
    } sh;
    __shared__ __align__(16) float wa_s[64 * 32];   // 8 KB

    const int tid  = threadIdx.x;
    const int lane = tid & 63;
    const int wv   = tid >> 6;
    const int c15  = lane & 15;     // score D col = query; PV D col = gi
    const int quad = lane >> 4;
    const int b    = blockIdx.y;
    const int n0   = blockIdx.x * 64;

    for (int i = tid; i < 2048; i += 256) wa_s[i] = Wa[i];

    // theta B-frag (const): B[k=quad*4+j][n=q]; real only for quads 0,1 (k<8)
    s4b zero4 = {0, 0, 0, 0};
    s4b bth = zero4;
    if (quad < 2) {
        union { uint2 u; s4b s; } t;
        t.u = *(const uint2*)&thT[((size_t)b * NN + n0 + wv * 16 + c15) * 8 + quad * 4];
        bth = t.s;
    }

    float4v acc0 = {0.f, 0.f, 0.f, 0.f};
    float4v acc1 = {0.f, 0.f, 0.f, 0.f};
    float zacc = 0.f;

    for (int ch = 0; ch < 4; ++ch) {
        __syncthreads();
        // stage phi: 256 keys x 8 bf16 (one uint4/thread) + zero the pad
        *(uint4*)&sh.m.phi[tid * 8] =
            *(const uint4*)&phiP[((size_t)b * MM + ch * 256 + tid) * 8];
        if (tid < 2) {
            uint4 z4; z4.x = z4.y = z4.z = z4.w = 0u;
            *(uint4*)&sh.m.phi[256 * 8 + tid * 8] = z4;
        }
        // stage g: 32 rows x 256 bf16 = 1024 uint4 (rows now 16B-aligned)
#pragma unroll
        for (int it = 0; it < 4; ++it) {
            const int idx = tid + 256 * it;
            const int row = idx >> 5, c32 = idx & 31;
            *(uint4*)&sh.m.g[row * GP + c32 * 8] =
                *(const uint4*)&gP[((size_t)b * 32 + row) * MM + ch * 256 + c32 * 8];
        }
        __syncthreads();

#pragma unroll 4
        for (int st = 0; st < 16; ++st) {
            const int kb = st * 16;   // key base within chunk

            // phi A-frag: A[m=key=c15][k=quad*4+j] (quads 2,3 read the next
            // key's finite data; theta B is zero there so it contributes 0)
            union { uint2 u; s4b s; } ap;
            ap.u = *(const uint2*)&sh.m.phi[(kb + c15) * 8 + quad * 4];

            float4v cz = {0.f, 0.f, 0.f, 0.f};
            float4v sc = mfma16(ap.s, bth, cz);   // D[key=quad*4+r][query=c15]

            // exp2 + Z + pack P (truncating bf16) -> PV A-frag in-register
            union { float f; unsigned u; } e0, e1, e2, e3;
            e0.f = __builtin_amdgcn_exp2f(sc[0]);
            e1.f = __builtin_amdgcn_exp2f(sc[1]);
            e2.f = __builtin_amdgcn_exp2f(sc[2]);
            e3.f = __builtin_amdgcn_exp2f(sc[3]);
            zacc += (e0.f + e1.f) + (e2.f + e3.f);
            union { uint2 u; s4b s; } pa;
            pa.u.x = __builtin_amdgcn_perm(e1.u, e0.u, 0x07060302u);
            pa.u.y = __builtin_amdgcn_perm(e3.u, e2.u, 0x07060302u);

            // g B-frags: B[k=quad*4+j][n=gi=c15] = g[gi][kb+quad*4+j]
            union { uint2 u; s4b s; } bg0, bg1;
            bg0.u = *(const uint2*)&sh.m.g[c15 * GP + kb + quad * 4];
            bg1.u = *(const uint2*)&sh.m.g[(16 + c15) * GP + kb + quad * 4];

            acc0 = mfma16(pa.s, bg0.s, acc0);   // D[q=quad*4+r][gi=c15]
            acc1 = mfma16(pa.s, bg1.s, acc1);   // gi = c15+16
        }
    }

    // full Z per query at every lane (q = c15)
    float z = zacc;
    z += __shfl_xor(z, 16, 64);
    z += __shfl_xor(z, 32, 64);
    const float rzq = __builtin_amdgcn_rcpf(z);

    __syncthreads();   // main-loop LDS reads done before obar overwrites

#pragma unroll
    for (int r = 0; r < 4; ++r) {
        const float rz = __shfl(rzq, quad * 4 + r, 64);  // Z of query quad*4+r
        const int ql = wv * 16 + quad * 4 + r;
        sh.obar[ql * OP + c15]      = acc0[r] * rz;
        sh.obar[ql * OP + 16 + c15] = acc1[r] * rz;
    }
    __syncthreads();

    // epilogue: out[o][n] = x + sigma * Wa[o][:] . obar[q][:]
    {
        const int q  = tid & 63;
        const int og = tid >> 6;    // 4 groups of 16 channels
        float a[16];
#pragma unroll
        for (int i = 0; i < 16; ++i) a[i] = 0.f;
        const float4* ob4 = (const float4*)&sh.obar[q * OP];   // q*144 B, 16B-aligned
        const float4* wa4 = (const float4*)wa_s;
#pragma unroll
        for (int g4 = 0; g4 < 8; ++g4) {
            const float4 ob = ob4[g4];
#pragma unroll
            for (int i = 0; i < 16; ++i) {
                const float4 w = wa4[(og * 16 + i) * 8 + g4];
                a[i] += w.x * ob.x + w.y * ob.y + w.z * ob.z + w.w * ob.w;
            }
        }
        const float sg = sigma[0];
#pragma unroll
        for (int i = 0; i < 16; ++i) {
            const size_t oi = ((size_t)b * CC + og * 16 + i) * NN + n0 + q;
            out[oi] = x[oi] + sg * a[i];
        }
    }
}

extern "C" void kernel_launch(void* const* d_in, const int* in_sizes, int n_in,
                              void* d_out, int out_size, void* d_ws, size_t ws_size,
                              hipStream_t stream) {
    const float* x      = (const float*)d_in[0];
    const float* W_th   = (const float*)d_in[1];
    const float* W_ph   = (const float*)d_in[2];
    const float* W_g    = (const float*)d_in[3];
    const float* W_attn = (const float*)d_in[4];
    const float* sigma  = (const float*)d_in[5];
    float* out = (float*)d_out;

    const int B = 16;
    unsigned short* thT  = (unsigned short*)d_ws;              // B*N*8
    unsigned short* phiP = thT + (size_t)B * NN * 8;           // B*M*8
    unsigned short* gP   = phiP + (size_t)B * MM * 8;          // B*32*M

    prep_kernel<<<dim3(32, 16), 256, 0, stream>>>(x, W_th, W_ph, W_g,
                                                  thT, phiP, gP);
    attn_mfma<<<dim3(64, 16), 256, 0, stream>>>(thT, phiP, gP, x,
                                                W_attn, sigma, out);
}